// Round 8
// baseline (289.254 us; speedup 1.0000x reference)
//
#include <hip/hip_runtime.h>
#include <math.h>

#define N_TS 4096
#define SEQ  168
#define HOR  24
#define T_ALL 192
#define F_INP 32
#define HID  64
#define NROW 192           // compacted gate rows: i(64) g(64) o(64)
#define NB_B (N_TS / 16)   // 256 autoregressive blocks (dispatched first)
#define L2E  1.44269504089f

typedef _Float16 half8  __attribute__((ext_vector_type(8)));
typedef _Float16 half4  __attribute__((ext_vector_type(4)));
typedef float    floatx4 __attribute__((ext_vector_type(4)));

__device__ __forceinline__ float fexp(float x)  { return __expf(x); }
__device__ __forceinline__ float ex2(float x)   { return __builtin_amdgcn_exp2f(x); }
__device__ __forceinline__ float frcp(float x)  { return __builtin_amdgcn_rcpf(x); }
__device__ __forceinline__ float softplus_(float x) { return (x > 15.0f) ? x : __logf(1.0f + fexp(x)); }

// Gates arrive PRESCALED: i,o rows x(-log2e); g rows x(-2*log2e) — folded into
// weights/biases, so every sigmoid/tanh exp is a bare v_exp (2^x).
__device__ __forceinline__ float lstm_h(float ip, float gp, float op) {
    const float Ei = ex2(ip);
    const float Eg = ex2(gp);
    const float cc = (1.0f - Eg) * frcp((1.0f + Ei) * (1.0f + Eg));
    const float Ec = ex2(cc * (-2.0f * L2E));
    const float Eo = ex2(op);
    return (1.0f - Ec) * frcp((1.0f + Ec) * (1.0f + Eo));
}

__device__ __forceinline__ half8 cvt8(const float4 a, const float4 b) {
    half8 v;
    v[0]=(_Float16)a.x; v[1]=(_Float16)a.y; v[2]=(_Float16)a.z; v[3]=(_Float16)a.w;
    v[4]=(_Float16)b.x; v[5]=(_Float16)b.y; v[6]=(_Float16)b.z; v[7]=(_Float16)b.w;
    return v;
}

// ---------------------------------------------------------------------------
// prep: compacted (f dropped), PRESCALED weights in k-chunked fragment layout
//   W16f[ ((l*8 + kb)*192 + row)*8 + kp ],  k = kb*8+kp.  bsum prescaled too.
// ---------------------------------------------------------------------------
__global__ __launch_bounds__(256) void prep(
    const float* __restrict__ W_ih, const float* __restrict__ b_ih,
    const float* __restrict__ b_hh,
    _Float16* __restrict__ W16f, float* __restrict__ bsum)
{
    const int idx = blockIdx.x * 256 + threadIdx.x;
    for (int i = idx; i < 2 * 8 * NROW * 8; i += gridDim.x * 256) {
        const int kp  = i & 7;
        const int row = (i >> 3) % NROW;
        const int kb  = ((i >> 3) / NROW) & 7;
        const int l   = i / (8 * NROW * 8);
        const int sr  = (row < 64) ? row : row + 64;   // skip dead f rows
        const float sc = (row >= 64 && row < 128) ? (-2.0f * L2E) : (-L2E);
        W16f[i] = (_Float16)(W_ih[(l * 256 + sr) * HID + kb * 8 + kp] * sc);
    }
    for (int i = idx; i < 2 * NROW; i += gridDim.x * 256) {
        const int r = i % NROW;
        const int l = i / NROW;
        const int sr = (r < 64) ? r : r + 64;
        const float sc = (r >= 64 && r < 128) ? (-2.0f * L2E) : (-L2E);
        bsum[i] = (b_ih[l * 256 + sr] + b_hh[l * 256 + sr]) * sc;
    }
}

// ---------------------------------------------------------------------------
// fused: blocks [0, NB_B) = autoregressive path (1 wave, 16 series, 25 steps
// incl. self-computed bootstrap at t=167 — no dependency on the other blocks);
// blocks [NB_B, ...) = teacher-forced path (r7 cellsA structure).
// LDS union: A=32768 B, B=52992 B -> 3 blocks/CU either way.
// ---------------------------------------------------------------------------
__global__ __launch_bounds__(256, 3) void fused(
    const float* __restrict__ X,
    const float* __restrict__ y,
    const float* __restrict__ Xf,
    const float* __restrict__ W_embed,
    const float* __restrict__ b_embed,
    const _Float16* __restrict__ W16f,
    const float* __restrict__ bsum,
    const float* __restrict__ W_mu,
    const float* __restrict__ b_mu,
    const float* __restrict__ W_sigma,
    const float* __restrict__ b_sigma,
    float* __restrict__ out)
{
    __shared__ union {
        struct { _Float16 Wl[12288]; _Float16 Hx[4][1024]; } A;              // 32768 B
        struct { _Float16 W1[12288]; _Float16 W2[12288];
                 _Float16 slab[16 * 72]; float b1[NROW]; float b2[NROW]; } B; // 52992 B
    } sh;

    const int tid = threadIdx.x;
    float* mu_out = out + (size_t)N_TS * HOR;
    float* sg_out = mu_out + (size_t)N_TS * T_ALL;

    if (blockIdx.x < NB_B) {
        // =================== autoregressive path (single wave) ===================
        if (tid >= 64) return;          // no barriers on this path: safe early-exit
        const int lane = tid;
        const int quad = lane >> 4;
        const int ln   = lane & 15;
        const int n0   = blockIdx.x * 16;

        // stage both layers' weights + biases into LDS (wave-private, in-order DS)
        #pragma unroll
        for (int c = 0; c < 48; ++c) {
            const int off = (c * 64 + lane) * 8;
            *(half8*)(sh.B.W1 + off) = *(const half8*)(W16f + off);   // W1|W2 contiguous
        }
        #pragma unroll
        for (int c = 0; c < 6; ++c)
            sh.B.b1[c * 64 + lane] = bsum[c * 64 + lane];             // b1|b2 contiguous
        __builtin_amdgcn_s_waitcnt(0);

        float we[8], be[8];
        #pragma unroll
        for (int e = 0; e < 8; ++e) {
            we[e] = W_embed[quad * 8 + e];
            be[e] = b_embed[quad * 8 + e];
        }
        float4 wmuv[4], wsgv[4];        // unit = jt*16 + quad*4 + r
        #pragma unroll
        for (int jt = 0; jt < 4; ++jt) {
            wmuv[jt] = *(const float4*)(W_mu + jt * 16 + quad * 4);
            wsgv[jt] = *(const float4*)(W_sigma + jt * 16 + quad * 4);
        }
        const float bmu = b_mu[0], bsg = b_sigma[0];

        // bootstrap inputs: t = 167 (teacher-forced), computed locally
        const float* xfp = Xf + (size_t)(n0 + ln) * HOR * F_INP + quad * 8;
        float yv = y[(size_t)(n0 + ln) * SEQ + (SEQ - 1)];
        float4 xa, xb;
        {
            const float* xp = X + ((size_t)(n0 + ln) * SEQ + (SEQ - 1)) * F_INP + quad * 8;
            xa = *(const float4*)xp;
            xb = *(const float4*)(xp + 4);
        }

        #pragma unroll 1
        for (int st = 0; st <= HOR; ++st) {      // st=0: bootstrap (no stores)
            const half8 xf0 = cvt8(xa, xb);
            if (st < HOR) {                      // prefetch next step's x (Xf step st)
                xa = *(const float4*)(xfp + st * F_INP);
                xb = *(const float4*)(xfp + st * F_INP + 4);
            }
            half8 xf1;                           // yembed slice for this lane's k-range
            #pragma unroll
            for (int e = 0; e < 8; ++e)
                xf1[e] = (_Float16)fmaf(yv, we[e], be[e]);

            // layer 1: 24 MFMAs, weights/biases from LDS
            floatx4 acc[12];
            #pragma unroll
            for (int nt = 0; nt < 12; ++nt) {
                acc[nt] = *(const floatx4*)(sh.B.b1 + nt * 16 + quad * 4);
                acc[nt] = __builtin_amdgcn_mfma_f32_16x16x32_f16(
                    *(const half8*)(sh.B.W1 + ((size_t)quad * NROW + nt * 16 + ln) * 8), xf0, acc[nt], 0, 0, 0);
                acc[nt] = __builtin_amdgcn_mfma_f32_16x16x32_f16(
                    *(const half8*)(sh.B.W1 + ((size_t)(4 + quad) * NROW + nt * 16 + ln) * 8), xf1, acc[nt], 0, 0, 0);
            }

            // act L1 -> slab (unit = jt*16+quad*4+r, series = ln)
            #pragma unroll
            for (int jt = 0; jt < 4; ++jt) {
                half4 hp;
                #pragma unroll
                for (int r = 0; r < 4; ++r)
                    hp[r] = (_Float16)lstm_h(acc[jt][r], acc[4 + jt][r], acc[8 + jt][r]);
                *(half4*)(&sh.B.slab[ln * 72 + jt * 16 + quad * 4]) = hp;
            }
            const half8 a0 = *(const half8*)(&sh.B.slab[ln * 72 + quad * 8]);
            const half8 a1 = *(const half8*)(&sh.B.slab[ln * 72 + 32 + quad * 8]);

            // layer 2
            #pragma unroll
            for (int nt = 0; nt < 12; ++nt) {
                floatx4 a = *(const floatx4*)(sh.B.b2 + nt * 16 + quad * 4);
                a = __builtin_amdgcn_mfma_f32_16x16x32_f16(
                    *(const half8*)(sh.B.W2 + ((size_t)quad * NROW + nt * 16 + ln) * 8), a0, a, 0, 0, 0);
                a = __builtin_amdgcn_mfma_f32_16x16x32_f16(
                    *(const half8*)(sh.B.W2 + ((size_t)(4 + quad) * NROW + nt * 16 + ln) * 8), a1, a, 0, 0, 0);
                acc[nt] = a;
            }

            // act L2 + heads
            float pm = 0.f, ps = 0.f;
            #pragma unroll
            for (int jt = 0; jt < 4; ++jt)
            #pragma unroll
            for (int r = 0; r < 4; ++r) {
                const float hh = lstm_h(acc[jt][r], acc[4 + jt][r], acc[8 + jt][r]);
                const float hr = fmaxf(hh, 0.0f);
                pm = fmaf(hr, ((const float*)&wmuv[jt])[r], pm);
                ps = fmaf(hr, ((const float*)&wsgv[jt])[r], ps);
            }
            pm += __shfl_xor(pm, 16, 64);  pm += __shfl_xor(pm, 32, 64);
            ps += __shfl_xor(ps, 16, 64);  ps += __shfl_xor(ps, 32, 64);

            const float mu = pm + bmu;
            const float sg = softplus_(ps + bsg) + 1e-6f;
            const float d  = yv - mu;
            const float is = frcp(sg);
            const float lik = 0.39894228040143267f * is * fexp(-0.5f * d * d * is * is);

            if (st > 0 && quad == 0) {           // bootstrap's outputs handled by A-path
                const int nn = n0 + ln;
                const int t  = SEQ + st - 1;
                mu_out[(size_t)nn * T_ALL + t] = mu;
                sg_out[(size_t)nn * T_ALL + t] = sg;
                if (st < HOR) out[(size_t)nn * HOR + st] = lik;
            }
            yv = lik;                            // bit-identical across quads
        }
        return;
    }

    // ======================= teacher-forced path =======================
    const int w    = tid >> 6;
    const int lane = tid & 63;
    const int quad = lane >> 4;
    const int ln   = lane & 15;
    const int cid0 = (blockIdx.x - NB_B) * 64 + w * 16;
    const int cid  = cid0 + ln;

    // ---- layer-0 A-frags straight from global ----
    half8 afr0, afr1;
    {
        const float* xp = X + (size_t)cid * F_INP + quad * 8;
        const float4 xa = *(const float4*)xp;
        const float4 xb = *(const float4*)(xp + 4);
        afr0 = cvt8(xa, xb);
        const float yv = y[cid];
        const float4 wa = *(const float4*)(W_embed + quad * 8);
        const float4 wb = *(const float4*)(W_embed + quad * 8 + 4);
        const float4 ba = *(const float4*)(b_embed + quad * 8);
        const float4 bb = *(const float4*)(b_embed + quad * 8 + 4);
        afr1[0]=(_Float16)fmaf(yv, wa.x, ba.x); afr1[1]=(_Float16)fmaf(yv, wa.y, ba.y);
        afr1[2]=(_Float16)fmaf(yv, wa.z, ba.z); afr1[3]=(_Float16)fmaf(yv, wa.w, ba.w);
        afr1[4]=(_Float16)fmaf(yv, wb.x, bb.x); afr1[5]=(_Float16)fmaf(yv, wb.y, bb.y);
        afr1[6]=(_Float16)fmaf(yv, wb.z, bb.z); afr1[7]=(_Float16)fmaf(yv, wb.w, bb.w);
    }

    // ---- stage layer-0 weights ----
    #pragma unroll
    for (int c = 0; c < 6; ++c) {
        const int off = (c * 256 + tid) * 8;
        *(half8*)(sh.A.Wl + off) = *(const half8*)(W16f + off);
    }
    __syncthreads();

    _Float16* hrow = sh.A.Hx[w];
    {
        const _Float16* bp = sh.A.Wl + quad * 1536 + ln * 8;
        #pragma unroll
        for (int jt = 0; jt < 4; ++jt) {
            const float bi = bsum[jt * 16 + ln];
            const float bg = bsum[(4 + jt) * 16 + ln];
            const float bo = bsum[(8 + jt) * 16 + ln];
            floatx4 ai = (floatx4){bi, bi, bi, bi};
            floatx4 ag = (floatx4){bg, bg, bg, bg};
            floatx4 ao = (floatx4){bo, bo, bo, bo};
            ai = __builtin_amdgcn_mfma_f32_16x16x32_f16(afr0, *(const half8*)(bp + jt * 128),              ai, 0, 0, 0);
            ai = __builtin_amdgcn_mfma_f32_16x16x32_f16(afr1, *(const half8*)(bp + jt * 128 + 6144),       ai, 0, 0, 0);
            ag = __builtin_amdgcn_mfma_f32_16x16x32_f16(afr0, *(const half8*)(bp + (4 + jt) * 128),        ag, 0, 0, 0);
            ag = __builtin_amdgcn_mfma_f32_16x16x32_f16(afr1, *(const half8*)(bp + (4 + jt) * 128 + 6144), ag, 0, 0, 0);
            ao = __builtin_amdgcn_mfma_f32_16x16x32_f16(afr0, *(const half8*)(bp + (8 + jt) * 128),        ao, 0, 0, 0);
            ao = __builtin_amdgcn_mfma_f32_16x16x32_f16(afr1, *(const half8*)(bp + (8 + jt) * 128 + 6144), ao, 0, 0, 0);
            #pragma unroll
            for (int r = 0; r < 4; ++r) {
                const float hh = lstm_h(ai[r], ag[r], ao[r]);
                const int row = quad * 4 + r;
                const int col = jt * 16 + ln;
                hrow[row * 64 + (((col >> 3) ^ (row & 7)) << 3) + (col & 7)] = (_Float16)hh;
            }
        }
    }

    const half8 a0 = *(const half8*)(hrow + ln * 64 + ((quad ^ (ln & 7)) << 3));
    const half8 a1 = *(const half8*)(hrow + ln * 64 + (((4 + quad) ^ (ln & 7)) << 3));

    __syncthreads();
    #pragma unroll
    for (int c = 0; c < 6; ++c) {
        const int off = (c * 256 + tid) * 8;
        *(half8*)(sh.A.Wl + off) = *(const half8*)(W16f + 12288 + off);
    }
    __syncthreads();

    float hfin[4][4];
    {
        const _Float16* bp = sh.A.Wl + quad * 1536 + ln * 8;
        #pragma unroll
        for (int jt = 0; jt < 4; ++jt) {
            const float bi = bsum[NROW + jt * 16 + ln];
            const float bg = bsum[NROW + (4 + jt) * 16 + ln];
            const float bo = bsum[NROW + (8 + jt) * 16 + ln];
            floatx4 ai = (floatx4){bi, bi, bi, bi};
            floatx4 ag = (floatx4){bg, bg, bg, bg};
            floatx4 ao = (floatx4){bo, bo, bo, bo};
            ai = __builtin_amdgcn_mfma_f32_16x16x32_f16(a0, *(const half8*)(bp + jt * 128),              ai, 0, 0, 0);
            ai = __builtin_amdgcn_mfma_f32_16x16x32_f16(a1, *(const half8*)(bp + jt * 128 + 6144),       ai, 0, 0, 0);
            ag = __builtin_amdgcn_mfma_f32_16x16x32_f16(a0, *(const half8*)(bp + (4 + jt) * 128),        ag, 0, 0, 0);
            ag = __builtin_amdgcn_mfma_f32_16x16x32_f16(a1, *(const half8*)(bp + (4 + jt) * 128 + 6144), ag, 0, 0, 0);
            ao = __builtin_amdgcn_mfma_f32_16x16x32_f16(a0, *(const half8*)(bp + (8 + jt) * 128),        ao, 0, 0, 0);
            ao = __builtin_amdgcn_mfma_f32_16x16x32_f16(a1, *(const half8*)(bp + (8 + jt) * 128 + 6144), ao, 0, 0, 0);
            #pragma unroll
            for (int r = 0; r < 4; ++r)
                hfin[jt][r] = lstm_h(ai[r], ag[r], ao[r]);
        }
    }

    // ---- heads ----
    float wmu[4], wsg[4];
    #pragma unroll
    for (int jt = 0; jt < 4; ++jt) {
        wmu[jt] = W_mu[jt * 16 + ln];
        wsg[jt] = W_sigma[jt * 16 + ln];
    }
    const float bmu = b_mu[0], bsg = b_sigma[0];

    #pragma unroll
    for (int r = 0; r < 4; ++r) {
        float pm = 0.f, ps = 0.f;
        #pragma unroll
        for (int jt = 0; jt < 4; ++jt) {
            const float hr = fmaxf(hfin[jt][r], 0.0f);
            pm = fmaf(hr, wmu[jt], pm);
            ps = fmaf(hr, wsg[jt], ps);
        }
        #pragma unroll
        for (int off = 1; off < 16; off <<= 1) {
            pm += __shfl_xor(pm, off, 64);
            ps += __shfl_xor(ps, off, 64);
        }
        if (ln == 0) {
            const int cid2 = cid0 + quad * 4 + r;
            const int n = cid2 / SEQ;
            const int t = cid2 - n * SEQ;
            const float mu = pm + bmu;
            const float sg = softplus_(ps + bsg) + 1e-6f;
            mu_out[(size_t)n * T_ALL + t] = mu;
            sg_out[(size_t)n * T_ALL + t] = sg;
            if (t == SEQ - 1) {
                const float yv = y[cid2];
                const float d  = yv - mu;
                const float is = frcp(sg);
                const float lik = 0.39894228040143267f * is * fexp(-0.5f * d * d * is * is);
                out[(size_t)n * HOR] = lik;
            }
        }
    }
}

extern "C" void kernel_launch(void* const* d_in, const int* in_sizes, int n_in,
                              void* d_out, int out_size, void* d_ws, size_t ws_size,
                              hipStream_t stream) {
    const float* X       = (const float*)d_in[0];
    const float* y       = (const float*)d_in[1];
    const float* Xf      = (const float*)d_in[2];
    const float* W_embed = (const float*)d_in[3];
    const float* b_embed = (const float*)d_in[4];
    const float* W_ih    = (const float*)d_in[5];
    const float* b_ih    = (const float*)d_in[6];
    const float* b_hh    = (const float*)d_in[7];
    const float* W_mu    = (const float*)d_in[8];
    const float* b_mu    = (const float*)d_in[9];
    const float* W_sigma = (const float*)d_in[10];
    const float* b_sigma = (const float*)d_in[11];

    float* out = (float*)d_out;
    // ws: W16f(49152 B) | bsum(1536 B)
    _Float16*  W16f = (_Float16*)d_ws;
    float*     bsum = (float*)((char*)d_ws + 49152);

    prep<<<96, 256, 0, stream>>>(W_ih, b_ih, b_hh, W16f, bsum);

    fused<<<NB_B + (N_TS * SEQ) / 64, 256, 0, stream>>>(
        X, y, Xf, W_embed, b_embed, W16f, bsum,
        W_mu, b_mu, W_sigma, b_sigma, out);
}

// Round 9
// 251.976 us; speedup vs baseline: 1.1479x; 1.1479x over previous
//
#include <hip/hip_runtime.h>
#include <math.h>

#define N_TS 4096
#define SEQ  168
#define HOR  24
#define T_ALL 192
#define F_INP 32
#define HID  64
#define NROW 192           // compacted gate rows: i(64) g(64) o(64)
#define NB_B (N_TS / 16)   // 256 autoregressive blocks (dispatched first)
#define L2E  1.44269504089f

typedef _Float16 half8  __attribute__((ext_vector_type(8)));
typedef _Float16 half4  __attribute__((ext_vector_type(4)));
typedef float    floatx4 __attribute__((ext_vector_type(4)));

__device__ __forceinline__ float fexp(float x)  { return __expf(x); }
__device__ __forceinline__ float ex2(float x)   { return __builtin_amdgcn_exp2f(x); }
__device__ __forceinline__ float frcp(float x)  { return __builtin_amdgcn_rcpf(x); }
__device__ __forceinline__ float softplus_(float x) { return (x > 15.0f) ? x : __logf(1.0f + fexp(x)); }

// Gates arrive PRESCALED: i,o rows x(-log2e); g rows x(-2*log2e) — folded into
// weights/biases, so every sigmoid/tanh exp is a bare v_exp (2^x).
__device__ __forceinline__ float lstm_h(float ip, float gp, float op) {
    const float Ei = ex2(ip);
    const float Eg = ex2(gp);
    const float cc = (1.0f - Eg) * frcp((1.0f + Ei) * (1.0f + Eg));
    const float Ec = ex2(cc * (-2.0f * L2E));
    const float Eo = ex2(op);
    return (1.0f - Ec) * frcp((1.0f + Ec) * (1.0f + Eo));
}

__device__ __forceinline__ half8 cvt8(const float4 a, const float4 b) {
    half8 v;
    v[0]=(_Float16)a.x; v[1]=(_Float16)a.y; v[2]=(_Float16)a.z; v[3]=(_Float16)a.w;
    v[4]=(_Float16)b.x; v[5]=(_Float16)b.y; v[6]=(_Float16)b.z; v[7]=(_Float16)b.w;
    return v;
}

// ---------------------------------------------------------------------------
// prep: compacted (f dropped), PRESCALED weights in k-chunked fragment layout
//   W16f[ ((l*8 + kb)*192 + row)*8 + kp ],  k = kb*8+kp.  bsum prescaled too.
// Rank-1 embed fold (prescaled): wy1 = W1[:,32:]@W_embed ; b1c = b1 + W1[:,32:]@b_embed.
// ---------------------------------------------------------------------------
__global__ __launch_bounds__(256) void prep(
    const float* __restrict__ W_ih, const float* __restrict__ b_ih,
    const float* __restrict__ b_hh,
    const float* __restrict__ W_embed, const float* __restrict__ b_embed,
    _Float16* __restrict__ W16f, float* __restrict__ bsum,
    float* __restrict__ wy1, float* __restrict__ b1c)
{
    const int idx = blockIdx.x * 256 + threadIdx.x;
    for (int i = idx; i < 2 * 8 * NROW * 8; i += gridDim.x * 256) {
        const int kp  = i & 7;
        const int row = (i >> 3) % NROW;
        const int kb  = ((i >> 3) / NROW) & 7;
        const int l   = i / (8 * NROW * 8);
        const int sr  = (row < 64) ? row : row + 64;   // skip dead f rows
        const float sc = (row >= 64 && row < 128) ? (-2.0f * L2E) : (-L2E);
        W16f[i] = (_Float16)(W_ih[(l * 256 + sr) * HID + kb * 8 + kp] * sc);
    }
    for (int i = idx; i < 2 * NROW; i += gridDim.x * 256) {
        const int r = i % NROW;
        const int l = i / NROW;
        const int sr = (r < 64) ? r : r + 64;
        const float sc = (r >= 64 && r < 128) ? (-2.0f * L2E) : (-L2E);
        bsum[i] = (b_ih[l * 256 + sr] + b_hh[l * 256 + sr]) * sc;
    }
    if (idx < NROW) {
        const int sr = (idx < 64) ? idx : idx + 64;
        const float sc = (idx >= 64 && idx < 128) ? (-2.0f * L2E) : (-L2E);
        const float* wrow = W_ih + sr * HID + 32;      // layer 0, cols 32..63
        float s1 = 0.f, s2 = 0.f;
        #pragma unroll
        for (int k = 0; k < 32; ++k) {
            s1 = fmaf(wrow[k], W_embed[k], s1);
            s2 = fmaf(wrow[k], b_embed[k], s2);
        }
        wy1[idx] = s1 * sc;
        b1c[idx] = (b_ih[sr] + b_hh[sr] + s2) * sc;
    }
}

// ---------------------------------------------------------------------------
// fused: blocks [0, NB_B) = autoregressive path — 4 waves, 16 series, 25 steps
// (step 0 = self-computed t=167 bootstrap, so no dependency on other blocks);
// r5-style: wave w owns row-tiles rt=j*4+w, W frags register-resident, rank-1
// embed fold, 3 barriers/step. Blocks [NB_B, ...) = r7 teacher-forced path.
// LDS union = 32768 B -> 5 blocks/CU both paths.
// ---------------------------------------------------------------------------
__global__ __launch_bounds__(256, 5) void fused(
    const float* __restrict__ X,
    const float* __restrict__ y,
    const float* __restrict__ Xf,
    const float* __restrict__ W_embed,
    const float* __restrict__ b_embed,
    const _Float16* __restrict__ W16f,
    const float* __restrict__ bsum,
    const float* __restrict__ wy1,
    const float* __restrict__ b1c,
    const float* __restrict__ W_mu,
    const float* __restrict__ b_mu,
    const float* __restrict__ W_sigma,
    const float* __restrict__ b_sigma,
    float* __restrict__ out)
{
    __shared__ union {
        struct { _Float16 Wl[12288]; _Float16 Hx[4][1024]; } A;      // 32768 B
        struct { _Float16 slab[16 * 72]; float partm[16][4]; float parts[16][4];
                 float ylds[16]; float wyb[NROW]; float b1cb[NROW]; } B; // ~4.5 KB
    } sh;

    const int tid = threadIdx.x;
    float* mu_out = out + (size_t)N_TS * HOR;
    float* sg_out = mu_out + (size_t)N_TS * T_ALL;

    if (blockIdx.x < NB_B) {
        // =================== autoregressive path (4 waves) ===================
        const int w    = tid >> 6;
        const int lane = tid & 63;
        const int quad = lane >> 4;
        const int ln   = lane & 15;
        const int n0   = blockIdx.x * 16;

        // stage step-invariant small data into LDS
        if (tid < NROW) {
            sh.B.wyb[tid]  = wy1[tid];
            sh.B.b1cb[tid] = b1c[tid];
        }
        if (tid < 16)
            sh.B.ylds[tid] = y[(size_t)(n0 + tid) * SEQ + (SEQ - 1)];

        // persistent register fragments (wave w owns row-tiles rt = j*4+w)
        half8 B1[3];        // W1 rows, k<32 (embed cols handled by rank-1 fold)
        half8 B2[3][2];     // W2 rows, full k
        float bias2[3];
        #pragma unroll
        for (int j = 0; j < 3; ++j) {
            const int rt = j * 4 + w;
            B1[j] = *(const half8*)(W16f + ((size_t)quad * NROW + rt * 16 + ln) * 8);
            #pragma unroll
            for (int kt = 0; kt < 2; ++kt)
                B2[j][kt] = *(const half8*)(W16f + 12288 + ((size_t)(kt * 4 + quad) * NROW + rt * 16 + ln) * 8);
            bias2[j] = bsum[NROW + rt * 16 + ln];
        }
        const float wmu = W_mu[w * 16 + ln], wsg = W_sigma[w * 16 + ln];
        const float bmu = b_mu[0], bsg = b_sigma[0];

        // bootstrap x: t = 167
        const float* xfp = Xf + (size_t)(n0 + ln) * HOR * F_INP + quad * 8;
        float4 xa, xb;
        {
            const float* xp = X + ((size_t)(n0 + ln) * SEQ + (SEQ - 1)) * F_INP + quad * 8;
            xa = *(const float4*)xp;
            xb = *(const float4*)(xp + 4);
        }
        __syncthreads();

        #pragma unroll 1
        for (int st = 0; st <= HOR; ++st) {      // st=0: bootstrap (no stores)
            const half8 xf0 = cvt8(xa, xb);
            if (st < HOR) {                      // next iter (st+1) uses Xf step st
                xa = *(const float4*)(xfp + st * F_INP);
                xb = *(const float4*)(xfp + st * F_INP + 4);
            }

            // layer 1: 3 MFMAs; C row = unit(quad*4+r in tile rt), col = series(ln)
            floatx4 t0 = *(const floatx4*)(sh.B.b1cb + 0 * 64 + w * 16 + quad * 4);
            floatx4 t1 = *(const floatx4*)(sh.B.b1cb + 1 * 64 + w * 16 + quad * 4);
            floatx4 t2 = *(const floatx4*)(sh.B.b1cb + 2 * 64 + w * 16 + quad * 4);
            t0 = __builtin_amdgcn_mfma_f32_16x16x32_f16(B1[0], xf0, t0, 0, 0, 0);
            t1 = __builtin_amdgcn_mfma_f32_16x16x32_f16(B1[1], xf0, t1, 0, 0, 0);
            t2 = __builtin_amdgcn_mfma_f32_16x16x32_f16(B1[2], xf0, t2, 0, 0, 0);

            const floatx4 wy0 = *(const floatx4*)(sh.B.wyb + 0 * 64 + w * 16 + quad * 4);
            const floatx4 wy1v = *(const floatx4*)(sh.B.wyb + 1 * 64 + w * 16 + quad * 4);
            const floatx4 wy2 = *(const floatx4*)(sh.B.wyb + 2 * 64 + w * 16 + quad * 4);
            const float yn = sh.B.ylds[ln];      // carry of series ln

            half4 h1p;
            #pragma unroll
            for (int r = 0; r < 4; ++r) {
                const float ig = fmaf(yn, wy0[r], t0[r]);
                const float gg = fmaf(yn, wy1v[r], t1[r]);
                const float og = fmaf(yn, wy2[r], t2[r]);
                h1p[r] = (_Float16)lstm_h(ig, gg, og);
            }
            *(half4*)(&sh.B.slab[ln * 72 + w * 16 + quad * 4]) = h1p;
            __syncthreads();

            // layer 2: A = h1 series-frag, B = register W2; C row=series, col=unit
            const half8 a0 = *(const half8*)(&sh.B.slab[ln * 72 + quad * 8]);
            const half8 a1 = *(const half8*)(&sh.B.slab[ln * 72 + 32 + quad * 8]);
            floatx4 acc[3];
            #pragma unroll
            for (int j = 0; j < 3; ++j) {
                acc[j] = (floatx4){bias2[j], bias2[j], bias2[j], bias2[j]};
                acc[j] = __builtin_amdgcn_mfma_f32_16x16x32_f16(a0, B2[j][0], acc[j], 0, 0, 0);
                acc[j] = __builtin_amdgcn_mfma_f32_16x16x32_f16(a1, B2[j][1], acc[j], 0, 0, 0);
            }

            // act L2 + head partials: unit w*16+ln, series quad*4+r
            float pmr[4], psr[4];
            #pragma unroll
            for (int r = 0; r < 4; ++r) {
                const float hh = lstm_h(acc[0][r], acc[1][r], acc[2][r]);
                const float hr = fmaxf(hh, 0.0f);
                pmr[r] = hr * wmu;
                psr[r] = hr * wsg;
            }
            #pragma unroll
            for (int off = 1; off < 16; off <<= 1) {
                #pragma unroll
                for (int r = 0; r < 4; ++r) {
                    pmr[r] += __shfl_xor(pmr[r], off, 64);
                    psr[r] += __shfl_xor(psr[r], off, 64);
                }
            }
            if (ln == 0) {
                #pragma unroll
                for (int r = 0; r < 4; ++r) {
                    sh.B.partm[quad * 4 + r][w] = pmr[r];
                    sh.B.parts[quad * 4 + r][w] = psr[r];
                }
            }
            __syncthreads();

            if (tid < 16) {                      // finalize series tid
                const float4 m4 = *(const float4*)sh.B.partm[tid];
                const float4 s4 = *(const float4*)sh.B.parts[tid];
                const float mu = (m4.x + m4.y) + (m4.z + m4.w) + bmu;
                const float sg = softplus_((s4.x + s4.y) + (s4.z + s4.w) + bsg) + 1e-6f;
                const float yv = sh.B.ylds[tid];
                const float d  = yv - mu;
                const float is = frcp(sg);
                const float lik = 0.39894228040143267f * is * fexp(-0.5f * d * d * is * is);
                if (st > 0) {                    // bootstrap outputs owned by A path
                    const int nn = n0 + tid;
                    const int t  = SEQ + st - 1;
                    mu_out[(size_t)nn * T_ALL + t] = mu;
                    sg_out[(size_t)nn * T_ALL + t] = sg;
                    if (st < HOR) out[(size_t)nn * HOR + st] = lik;
                }
                sh.B.ylds[tid] = lik;
            }
            __syncthreads();
        }
        return;
    }

    // ======================= teacher-forced path (r7) =======================
    const int w    = tid >> 6;
    const int lane = tid & 63;
    const int quad = lane >> 4;
    const int ln   = lane & 15;
    const int cid0 = (blockIdx.x - NB_B) * 64 + w * 16;
    const int cid  = cid0 + ln;

    // ---- layer-0 A-frags straight from global ----
    half8 afr0, afr1;
    {
        const float* xp = X + (size_t)cid * F_INP + quad * 8;
        const float4 xa = *(const float4*)xp;
        const float4 xb = *(const float4*)(xp + 4);
        afr0 = cvt8(xa, xb);
        const float yv = y[cid];
        const float4 wa = *(const float4*)(W_embed + quad * 8);
        const float4 wb = *(const float4*)(W_embed + quad * 8 + 4);
        const float4 ba = *(const float4*)(b_embed + quad * 8);
        const float4 bb = *(const float4*)(b_embed + quad * 8 + 4);
        afr1[0]=(_Float16)fmaf(yv, wa.x, ba.x); afr1[1]=(_Float16)fmaf(yv, wa.y, ba.y);
        afr1[2]=(_Float16)fmaf(yv, wa.z, ba.z); afr1[3]=(_Float16)fmaf(yv, wa.w, ba.w);
        afr1[4]=(_Float16)fmaf(yv, wb.x, bb.x); afr1[5]=(_Float16)fmaf(yv, wb.y, bb.y);
        afr1[6]=(_Float16)fmaf(yv, wb.z, bb.z); afr1[7]=(_Float16)fmaf(yv, wb.w, bb.w);
    }

    // ---- stage layer-0 weights ----
    #pragma unroll
    for (int c = 0; c < 6; ++c) {
        const int off = (c * 256 + tid) * 8;
        *(half8*)(sh.A.Wl + off) = *(const half8*)(W16f + off);
    }
    __syncthreads();

    _Float16* hrow = sh.A.Hx[w];
    {
        const _Float16* bp = sh.A.Wl + quad * 1536 + ln * 8;
        #pragma unroll
        for (int jt = 0; jt < 4; ++jt) {
            const float bi = bsum[jt * 16 + ln];
            const float bg = bsum[(4 + jt) * 16 + ln];
            const float bo = bsum[(8 + jt) * 16 + ln];
            floatx4 ai = (floatx4){bi, bi, bi, bi};
            floatx4 ag = (floatx4){bg, bg, bg, bg};
            floatx4 ao = (floatx4){bo, bo, bo, bo};
            ai = __builtin_amdgcn_mfma_f32_16x16x32_f16(afr0, *(const half8*)(bp + jt * 128),              ai, 0, 0, 0);
            ai = __builtin_amdgcn_mfma_f32_16x16x32_f16(afr1, *(const half8*)(bp + jt * 128 + 6144),       ai, 0, 0, 0);
            ag = __builtin_amdgcn_mfma_f32_16x16x32_f16(afr0, *(const half8*)(bp + (4 + jt) * 128),        ag, 0, 0, 0);
            ag = __builtin_amdgcn_mfma_f32_16x16x32_f16(afr1, *(const half8*)(bp + (4 + jt) * 128 + 6144), ag, 0, 0, 0);
            ao = __builtin_amdgcn_mfma_f32_16x16x32_f16(afr0, *(const half8*)(bp + (8 + jt) * 128),        ao, 0, 0, 0);
            ao = __builtin_amdgcn_mfma_f32_16x16x32_f16(afr1, *(const half8*)(bp + (8 + jt) * 128 + 6144), ao, 0, 0, 0);
            #pragma unroll
            for (int r = 0; r < 4; ++r) {
                const float hh = lstm_h(ai[r], ag[r], ao[r]);
                const int row = quad * 4 + r;
                const int col = jt * 16 + ln;
                hrow[row * 64 + (((col >> 3) ^ (row & 7)) << 3) + (col & 7)] = (_Float16)hh;
            }
        }
    }

    const half8 a0 = *(const half8*)(hrow + ln * 64 + ((quad ^ (ln & 7)) << 3));
    const half8 a1 = *(const half8*)(hrow + ln * 64 + (((4 + quad) ^ (ln & 7)) << 3));

    __syncthreads();
    #pragma unroll
    for (int c = 0; c < 6; ++c) {
        const int off = (c * 256 + tid) * 8;
        *(half8*)(sh.A.Wl + off) = *(const half8*)(W16f + 12288 + off);
    }
    __syncthreads();

    float hfin[4][4];
    {
        const _Float16* bp = sh.A.Wl + quad * 1536 + ln * 8;
        #pragma unroll
        for (int jt = 0; jt < 4; ++jt) {
            const float bi = bsum[NROW + jt * 16 + ln];
            const float bg = bsum[NROW + (4 + jt) * 16 + ln];
            const float bo = bsum[NROW + (8 + jt) * 16 + ln];
            floatx4 ai = (floatx4){bi, bi, bi, bi};
            floatx4 ag = (floatx4){bg, bg, bg, bg};
            floatx4 ao = (floatx4){bo, bo, bo, bo};
            ai = __builtin_amdgcn_mfma_f32_16x16x32_f16(a0, *(const half8*)(bp + jt * 128),              ai, 0, 0, 0);
            ai = __builtin_amdgcn_mfma_f32_16x16x32_f16(a1, *(const half8*)(bp + jt * 128 + 6144),       ai, 0, 0, 0);
            ag = __builtin_amdgcn_mfma_f32_16x16x32_f16(a0, *(const half8*)(bp + (4 + jt) * 128),        ag, 0, 0, 0);
            ag = __builtin_amdgcn_mfma_f32_16x16x32_f16(a1, *(const half8*)(bp + (4 + jt) * 128 + 6144), ag, 0, 0, 0);
            ao = __builtin_amdgcn_mfma_f32_16x16x32_f16(a0, *(const half8*)(bp + (8 + jt) * 128),        ao, 0, 0, 0);
            ao = __builtin_amdgcn_mfma_f32_16x16x32_f16(a1, *(const half8*)(bp + (8 + jt) * 128 + 6144), ao, 0, 0, 0);
            #pragma unroll
            for (int r = 0; r < 4; ++r)
                hfin[jt][r] = lstm_h(ai[r], ag[r], ao[r]);
        }
    }

    // ---- heads ----
    float wmu[4], wsg[4];
    #pragma unroll
    for (int jt = 0; jt < 4; ++jt) {
        wmu[jt] = W_mu[jt * 16 + ln];
        wsg[jt] = W_sigma[jt * 16 + ln];
    }
    const float bmu = b_mu[0], bsg = b_sigma[0];

    #pragma unroll
    for (int r = 0; r < 4; ++r) {
        float pm = 0.f, ps = 0.f;
        #pragma unroll
        for (int jt = 0; jt < 4; ++jt) {
            const float hr = fmaxf(hfin[jt][r], 0.0f);
            pm = fmaf(hr, wmu[jt], pm);
            ps = fmaf(hr, wsg[jt], ps);
        }
        #pragma unroll
        for (int off = 1; off < 16; off <<= 1) {
            pm += __shfl_xor(pm, off, 64);
            ps += __shfl_xor(ps, off, 64);
        }
        if (ln == 0) {
            const int cid2 = cid0 + quad * 4 + r;
            const int n = cid2 / SEQ;
            const int t = cid2 - n * SEQ;
            const float mu = pm + bmu;
            const float sg = softplus_(ps + bsg) + 1e-6f;
            mu_out[(size_t)n * T_ALL + t] = mu;
            sg_out[(size_t)n * T_ALL + t] = sg;
            if (t == SEQ - 1) {
                const float yv = y[cid2];
                const float d  = yv - mu;
                const float is = frcp(sg);
                const float lik = 0.39894228040143267f * is * fexp(-0.5f * d * d * is * is);
                out[(size_t)n * HOR] = lik;
            }
        }
    }
}

extern "C" void kernel_launch(void* const* d_in, const int* in_sizes, int n_in,
                              void* d_out, int out_size, void* d_ws, size_t ws_size,
                              hipStream_t stream) {
    const float* X       = (const float*)d_in[0];
    const float* y       = (const float*)d_in[1];
    const float* Xf      = (const float*)d_in[2];
    const float* W_embed = (const float*)d_in[3];
    const float* b_embed = (const float*)d_in[4];
    const float* W_ih    = (const float*)d_in[5];
    const float* b_ih    = (const float*)d_in[6];
    const float* b_hh    = (const float*)d_in[7];
    const float* W_mu    = (const float*)d_in[8];
    const float* b_mu    = (const float*)d_in[9];
    const float* W_sigma = (const float*)d_in[10];
    const float* b_sigma = (const float*)d_in[11];

    float* out = (float*)d_out;
    // ws: W16f(49152 B) | bsum(1536 B) | wy1(768 B) | b1c(768 B)
    _Float16*  W16f = (_Float16*)d_ws;
    float*     bsum = (float*)((char*)d_ws + 49152);
    float*     wy1  = (float*)((char*)d_ws + 49152 + 1536);
    float*     b1c  = (float*)((char*)d_ws + 49152 + 1536 + 768);

    prep<<<96, 256, 0, stream>>>(W_ih, b_ih, b_hh, W_embed, b_embed,
                                 W16f, bsum, wy1, b1c);

    fused<<<NB_B + (N_TS * SEQ) / 64, 256, 0, stream>>>(
        X, y, Xf, W_embed, b_embed, W16f, bsum, wy1, b1c,
        W_mu, b_mu, W_sigma, b_sigma, out);
}

// Round 10
// 247.920 us; speedup vs baseline: 1.1667x; 1.0164x over previous
//
#include <hip/hip_runtime.h>
#include <math.h>

#define N_TS 4096
#define SEQ  168
#define HOR  24
#define T_ALL 192
#define F_INP 32
#define HID  64
#define NROW 192           // compacted gate rows: i(64) g(64) o(64)
#define NB_B (N_TS / 16)   // 256 autoregressive blocks (dispatched first)
#define L2E  1.44269504089f

typedef _Float16 half8  __attribute__((ext_vector_type(8)));
typedef _Float16 half4  __attribute__((ext_vector_type(4)));
typedef float    floatx4 __attribute__((ext_vector_type(4)));

__device__ __forceinline__ float fexp(float x)  { return __expf(x); }
__device__ __forceinline__ float ex2(float x)   { return __builtin_amdgcn_exp2f(x); }
__device__ __forceinline__ float frcp(float x)  { return __builtin_amdgcn_rcpf(x); }
__device__ __forceinline__ float softplus_(float x) { return (x > 15.0f) ? x : __logf(1.0f + fexp(x)); }

// Gates arrive PRESCALED: i,o rows x(-log2e); g rows x(-2*log2e) — folded into
// weights/biases, so every sigmoid/tanh exp is a bare v_exp (2^x).
__device__ __forceinline__ float lstm_h(float ip, float gp, float op) {
    const float Ei = ex2(ip);
    const float Eg = ex2(gp);
    const float cc = (1.0f - Eg) * frcp((1.0f + Ei) * (1.0f + Eg));
    const float Ec = ex2(cc * (-2.0f * L2E));
    const float Eo = ex2(op);
    return (1.0f - Ec) * frcp((1.0f + Ec) * (1.0f + Eo));
}

__device__ __forceinline__ half8 cvt8(const float4 a, const float4 b) {
    half8 v;
    v[0]=(_Float16)a.x; v[1]=(_Float16)a.y; v[2]=(_Float16)a.z; v[3]=(_Float16)a.w;
    v[4]=(_Float16)b.x; v[5]=(_Float16)b.y; v[6]=(_Float16)b.z; v[7]=(_Float16)b.w;
    return v;
}

// ---------------------------------------------------------------------------
// prep: compacted (f dropped), PRESCALED weights in k-chunked fragment layout
//   W16f[ ((l*8 + kb)*192 + row)*8 + kp ],  k = kb*8+kp.  bsum prescaled too.
// Rank-1 embed fold (prescaled): wy1 = W1[:,32:]@W_embed ; b1c = b1 + W1[:,32:]@b_embed.
// ---------------------------------------------------------------------------
__global__ __launch_bounds__(256) void prep(
    const float* __restrict__ W_ih, const float* __restrict__ b_ih,
    const float* __restrict__ b_hh,
    const float* __restrict__ W_embed, const float* __restrict__ b_embed,
    _Float16* __restrict__ W16f, float* __restrict__ bsum,
    float* __restrict__ wy1, float* __restrict__ b1c)
{
    const int idx = blockIdx.x * 256 + threadIdx.x;
    for (int i = idx; i < 2 * 8 * NROW * 8; i += gridDim.x * 256) {
        const int kp  = i & 7;
        const int row = (i >> 3) % NROW;
        const int kb  = ((i >> 3) / NROW) & 7;
        const int l   = i / (8 * NROW * 8);
        const int sr  = (row < 64) ? row : row + 64;   // skip dead f rows
        const float sc = (row >= 64 && row < 128) ? (-2.0f * L2E) : (-L2E);
        W16f[i] = (_Float16)(W_ih[(l * 256 + sr) * HID + kb * 8 + kp] * sc);
    }
    for (int i = idx; i < 2 * NROW; i += gridDim.x * 256) {
        const int r = i % NROW;
        const int l = i / NROW;
        const int sr = (r < 64) ? r : r + 64;
        const float sc = (r >= 64 && r < 128) ? (-2.0f * L2E) : (-L2E);
        bsum[i] = (b_ih[l * 256 + sr] + b_hh[l * 256 + sr]) * sc;
    }
    if (idx < NROW) {
        const int sr = (idx < 64) ? idx : idx + 64;
        const float sc = (idx >= 64 && idx < 128) ? (-2.0f * L2E) : (-L2E);
        const float* wrow = W_ih + sr * HID + 32;      // layer 0, cols 32..63
        float s1 = 0.f, s2 = 0.f;
        #pragma unroll
        for (int k = 0; k < 32; ++k) {
            s1 = fmaf(wrow[k], W_embed[k], s1);
            s2 = fmaf(wrow[k], b_embed[k], s2);
        }
        wy1[idx] = s1 * sc;
        b1c[idx] = (b_ih[sr] + b_hh[sr] + s2) * sc;
    }
}

// ---------------------------------------------------------------------------
// fused: blocks [0, NB_B) = autoregressive path — 4 waves, 16 series, 25 steps
// (step 0 = self-computed t=167 bootstrap). s_setprio(1), XOR-swizzled h1
// slab (b128-floor balanced), 2 barriers/step, carry recomputed redundantly
// per-lane from head partials (no serial finalize).
// Blocks [NB_B, ...) = r7 teacher-forced path (byte-identical to r9).
// LDS union = 32768 B -> 5 blocks/CU both paths.
// ---------------------------------------------------------------------------
__global__ __launch_bounds__(256, 5) void fused(
    const float* __restrict__ X,
    const float* __restrict__ y,
    const float* __restrict__ Xf,
    const float* __restrict__ W_embed,
    const float* __restrict__ b_embed,
    const _Float16* __restrict__ W16f,
    const float* __restrict__ bsum,
    const float* __restrict__ wy1,
    const float* __restrict__ b1c,
    const float* __restrict__ W_mu,
    const float* __restrict__ b_mu,
    const float* __restrict__ W_sigma,
    const float* __restrict__ b_sigma,
    float* __restrict__ out)
{
    __shared__ union __align__(16) {
        struct { _Float16 Wl[12288]; _Float16 Hx[4][1024]; } A;      // 32768 B
        struct { _Float16 slab[16 * 64]; float partm[16][4]; float parts[16][4];
                 float wyb[NROW]; float b1cb[NROW]; } B;             // ~4.1 KB
    } sh;

    const int tid = threadIdx.x;
    float* mu_out = out + (size_t)N_TS * HOR;
    float* sg_out = mu_out + (size_t)N_TS * T_ALL;

    if (blockIdx.x < NB_B) {
        // =================== autoregressive path (4 waves) ===================
        __builtin_amdgcn_s_setprio(1);           // beat co-resident A waves
        const int w    = tid >> 6;
        const int lane = tid & 63;
        const int quad = lane >> 4;
        const int ln   = lane & 15;
        const int n0   = blockIdx.x * 16;

        if (tid < NROW) {
            sh.B.wyb[tid]  = wy1[tid];
            sh.B.b1cb[tid] = b1c[tid];
        }

        // persistent register fragments (wave w owns row-tiles rt = j*4+w)
        half8 B1[3];        // W1 rows, k<32 (embed cols via rank-1 fold)
        half8 B2[3][2];     // W2 rows, full k
        float bias2[3];
        #pragma unroll
        for (int j = 0; j < 3; ++j) {
            const int rt = j * 4 + w;
            B1[j] = *(const half8*)(W16f + ((size_t)quad * NROW + rt * 16 + ln) * 8);
            #pragma unroll
            for (int kt = 0; kt < 2; ++kt)
                B2[j][kt] = *(const half8*)(W16f + 12288 + ((size_t)(kt * 4 + quad) * NROW + rt * 16 + ln) * 8);
            bias2[j] = bsum[NROW + rt * 16 + ln];
        }
        const float wmu = W_mu[w * 16 + ln], wsg = W_sigma[w * 16 + ln];
        const float bmu = b_mu[0], bsg = b_sigma[0];

        // bootstrap inputs: t = 167
        const float* xfp = Xf + (size_t)(n0 + ln) * HOR * F_INP + quad * 8;
        float4 xa, xb;
        {
            const float* xp = X + ((size_t)(n0 + ln) * SEQ + (SEQ - 1)) * F_INP + quad * 8;
            xa = *(const float4*)xp;
            xb = *(const float4*)(xp + 4);
        }
        float ycur = y[(size_t)(n0 + ln) * SEQ + (SEQ - 1)];
        __syncthreads();                         // wyb/b1cb visible

        #pragma unroll 1
        for (int it = 0; it <= HOR + 1; ++it) {
            if (it > 0) {
                // finalize step k = it-1 (redundant per-lane, bit-identical)
                const int k = it - 1;
                const float4 m4 = *(const float4*)sh.B.partm[ln];
                const float4 s4 = *(const float4*)sh.B.parts[ln];
                const float mu = (m4.x + m4.y) + (m4.z + m4.w) + bmu;
                const float sg = softplus_((s4.x + s4.y) + (s4.z + s4.w) + bsg) + 1e-6f;
                const float d  = ycur - mu;
                const float is = frcp(sg);
                const float lik = 0.39894228040143267f * is * fexp(-0.5f * d * d * is * is);
                if (k > 0 && w == 0 && quad == 0) {
                    const int nn = n0 + ln;
                    const int t  = SEQ + k - 1;
                    mu_out[(size_t)nn * T_ALL + t] = mu;
                    sg_out[(size_t)nn * T_ALL + t] = sg;
                    if (k < HOR) out[(size_t)nn * HOR + k] = lik;
                }
                ycur = lik;
            }
            if (it > HOR) break;

            // ---- compute step it (input carry = ycur) ----
            const half8 xf0 = cvt8(xa, xb);
            if (it < HOR) {                      // next iter uses Xf step it
                xa = *(const float4*)(xfp + it * F_INP);
                xb = *(const float4*)(xfp + it * F_INP + 4);
            }

            // layer 1: 3 MFMAs; C row = unit-in-tile (quad*4+r), col = series(ln)
            floatx4 t0 = *(const floatx4*)(sh.B.b1cb + 0 * 64 + w * 16 + quad * 4);
            floatx4 t1 = *(const floatx4*)(sh.B.b1cb + 1 * 64 + w * 16 + quad * 4);
            floatx4 t2 = *(const floatx4*)(sh.B.b1cb + 2 * 64 + w * 16 + quad * 4);
            t0 = __builtin_amdgcn_mfma_f32_16x16x32_f16(B1[0], xf0, t0, 0, 0, 0);
            t1 = __builtin_amdgcn_mfma_f32_16x16x32_f16(B1[1], xf0, t1, 0, 0, 0);
            t2 = __builtin_amdgcn_mfma_f32_16x16x32_f16(B1[2], xf0, t2, 0, 0, 0);

            const floatx4 wy0 = *(const floatx4*)(sh.B.wyb + 0 * 64 + w * 16 + quad * 4);
            const floatx4 wy1v = *(const floatx4*)(sh.B.wyb + 1 * 64 + w * 16 + quad * 4);
            const floatx4 wy2 = *(const floatx4*)(sh.B.wyb + 2 * 64 + w * 16 + quad * 4);

            half4 h1p;
            #pragma unroll
            for (int r = 0; r < 4; ++r) {
                const float ig = fmaf(ycur, wy0[r], t0[r]);
                const float gg = fmaf(ycur, wy1v[r], t1[r]);
                const float og = fmaf(ycur, wy2[r], t2[r]);
                h1p[r] = (_Float16)lstm_h(ig, gg, og);
            }
            // XOR-swizzled slab write: unit block ublk = 2w + (quad>>1)
            {
                const int xblk = (2 * w + (quad >> 1)) ^ (ln & 7);
                *(half4*)(&sh.B.slab[ln * 64 + xblk * 8 + (quad & 1) * 4]) = h1p;
            }
            __syncthreads();

            // layer 2: A = h1 series-frag (swizzled reads, b128-floor balanced)
            const half8 a0 = *(const half8*)(&sh.B.slab[ln * 64 + ((quad ^ (ln & 7)) << 3)]);
            const half8 a1 = *(const half8*)(&sh.B.slab[ln * 64 + (((4 + quad) ^ (ln & 7)) << 3)]);
            floatx4 acc[3];
            #pragma unroll
            for (int j = 0; j < 3; ++j) {
                acc[j] = (floatx4){bias2[j], bias2[j], bias2[j], bias2[j]};
                acc[j] = __builtin_amdgcn_mfma_f32_16x16x32_f16(a0, B2[j][0], acc[j], 0, 0, 0);
                acc[j] = __builtin_amdgcn_mfma_f32_16x16x32_f16(a1, B2[j][1], acc[j], 0, 0, 0);
            }

            // act L2 + head partials: unit w*16+ln, series quad*4+r
            float pmr[4], psr[4];
            #pragma unroll
            for (int r = 0; r < 4; ++r) {
                const float hh = lstm_h(acc[0][r], acc[1][r], acc[2][r]);
                const float hr = fmaxf(hh, 0.0f);
                pmr[r] = hr * wmu;
                psr[r] = hr * wsg;
            }
            #pragma unroll
            for (int off = 1; off < 16; off <<= 1) {
                #pragma unroll
                for (int r = 0; r < 4; ++r) {
                    pmr[r] += __shfl_xor(pmr[r], off, 64);
                    psr[r] += __shfl_xor(psr[r], off, 64);
                }
            }
            if (ln == 0) {
                #pragma unroll
                for (int r = 0; r < 4; ++r) {
                    sh.B.partm[quad * 4 + r][w] = pmr[r];
                    sh.B.parts[quad * 4 + r][w] = psr[r];
                }
            }
            __syncthreads();
        }
        return;
    }

    // ======================= teacher-forced path (r7) =======================
    const int w    = tid >> 6;
    const int lane = tid & 63;
    const int quad = lane >> 4;
    const int ln   = lane & 15;
    const int cid0 = (blockIdx.x - NB_B) * 64 + w * 16;
    const int cid  = cid0 + ln;

    // ---- layer-0 A-frags straight from global ----
    half8 afr0, afr1;
    {
        const float* xp = X + (size_t)cid * F_INP + quad * 8;
        const float4 xa = *(const float4*)xp;
        const float4 xb = *(const float4*)(xp + 4);
        afr0 = cvt8(xa, xb);
        const float yv = y[cid];
        const float4 wa = *(const float4*)(W_embed + quad * 8);
        const float4 wb = *(const float4*)(W_embed + quad * 8 + 4);
        const float4 ba = *(const float4*)(b_embed + quad * 8);
        const float4 bb = *(const float4*)(b_embed + quad * 8 + 4);
        afr1[0]=(_Float16)fmaf(yv, wa.x, ba.x); afr1[1]=(_Float16)fmaf(yv, wa.y, ba.y);
        afr1[2]=(_Float16)fmaf(yv, wa.z, ba.z); afr1[3]=(_Float16)fmaf(yv, wa.w, ba.w);
        afr1[4]=(_Float16)fmaf(yv, wb.x, bb.x); afr1[5]=(_Float16)fmaf(yv, wb.y, bb.y);
        afr1[6]=(_Float16)fmaf(yv, wb.z, bb.z); afr1[7]=(_Float16)fmaf(yv, wb.w, bb.w);
    }

    // ---- stage layer-0 weights ----
    #pragma unroll
    for (int c = 0; c < 6; ++c) {
        const int off = (c * 256 + tid) * 8;
        *(half8*)(sh.A.Wl + off) = *(const half8*)(W16f + off);
    }
    __syncthreads();

    _Float16* hrow = sh.A.Hx[w];
    {
        const _Float16* bp = sh.A.Wl + quad * 1536 + ln * 8;
        #pragma unroll
        for (int jt = 0; jt < 4; ++jt) {
            const float bi = bsum[jt * 16 + ln];
            const float bg = bsum[(4 + jt) * 16 + ln];
            const float bo = bsum[(8 + jt) * 16 + ln];
            floatx4 ai = (floatx4){bi, bi, bi, bi};
            floatx4 ag = (floatx4){bg, bg, bg, bg};
            floatx4 ao = (floatx4){bo, bo, bo, bo};
            ai = __builtin_amdgcn_mfma_f32_16x16x32_f16(afr0, *(const half8*)(bp + jt * 128),              ai, 0, 0, 0);
            ai = __builtin_amdgcn_mfma_f32_16x16x32_f16(afr1, *(const half8*)(bp + jt * 128 + 6144),       ai, 0, 0, 0);
            ag = __builtin_amdgcn_mfma_f32_16x16x32_f16(afr0, *(const half8*)(bp + (4 + jt) * 128),        ag, 0, 0, 0);
            ag = __builtin_amdgcn_mfma_f32_16x16x32_f16(afr1, *(const half8*)(bp + (4 + jt) * 128 + 6144), ag, 0, 0, 0);
            ao = __builtin_amdgcn_mfma_f32_16x16x32_f16(afr0, *(const half8*)(bp + (8 + jt) * 128),        ao, 0, 0, 0);
            ao = __builtin_amdgcn_mfma_f32_16x16x32_f16(afr1, *(const half8*)(bp + (8 + jt) * 128 + 6144), ao, 0, 0, 0);
            #pragma unroll
            for (int r = 0; r < 4; ++r) {
                const float hh = lstm_h(ai[r], ag[r], ao[r]);
                const int row = quad * 4 + r;
                const int col = jt * 16 + ln;
                hrow[row * 64 + (((col >> 3) ^ (row & 7)) << 3) + (col & 7)] = (_Float16)hh;
            }
        }
    }

    const half8 a0 = *(const half8*)(hrow + ln * 64 + ((quad ^ (ln & 7)) << 3));
    const half8 a1 = *(const half8*)(hrow + ln * 64 + (((4 + quad) ^ (ln & 7)) << 3));

    __syncthreads();
    #pragma unroll
    for (int c = 0; c < 6; ++c) {
        const int off = (c * 256 + tid) * 8;
        *(half8*)(sh.A.Wl + off) = *(const half8*)(W16f + 12288 + off);
    }
    __syncthreads();

    float hfin[4][4];
    {
        const _Float16* bp = sh.A.Wl + quad * 1536 + ln * 8;
        #pragma unroll
        for (int jt = 0; jt < 4; ++jt) {
            const float bi = bsum[NROW + jt * 16 + ln];
            const float bg = bsum[NROW + (4 + jt) * 16 + ln];
            const float bo = bsum[NROW + (8 + jt) * 16 + ln];
            floatx4 ai = (floatx4){bi, bi, bi, bi};
            floatx4 ag = (floatx4){bg, bg, bg, bg};
            floatx4 ao = (floatx4){bo, bo, bo, bo};
            ai = __builtin_amdgcn_mfma_f32_16x16x32_f16(a0, *(const half8*)(bp + jt * 128),              ai, 0, 0, 0);
            ai = __builtin_amdgcn_mfma_f32_16x16x32_f16(a1, *(const half8*)(bp + jt * 128 + 6144),       ai, 0, 0, 0);
            ag = __builtin_amdgcn_mfma_f32_16x16x32_f16(a0, *(const half8*)(bp + (4 + jt) * 128),        ag, 0, 0, 0);
            ag = __builtin_amdgcn_mfma_f32_16x16x32_f16(a1, *(const half8*)(bp + (4 + jt) * 128 + 6144), ag, 0, 0, 0);
            ao = __builtin_amdgcn_mfma_f32_16x16x32_f16(a0, *(const half8*)(bp + (8 + jt) * 128),        ao, 0, 0, 0);
            ao = __builtin_amdgcn_mfma_f32_16x16x32_f16(a1, *(const half8*)(bp + (8 + jt) * 128 + 6144), ao, 0, 0, 0);
            #pragma unroll
            for (int r = 0; r < 4; ++r)
                hfin[jt][r] = lstm_h(ai[r], ag[r], ao[r]);
        }
    }

    // ---- heads ----
    float wmu[4], wsg[4];
    #pragma unroll
    for (int jt = 0; jt < 4; ++jt) {
        wmu[jt] = W_mu[jt * 16 + ln];
        wsg[jt] = W_sigma[jt * 16 + ln];
    }
    const float bmu = b_mu[0], bsg = b_sigma[0];

    #pragma unroll
    for (int r = 0; r < 4; ++r) {
        float pm = 0.f, ps = 0.f;
        #pragma unroll
        for (int jt = 0; jt < 4; ++jt) {
            const float hr = fmaxf(hfin[jt][r], 0.0f);
            pm = fmaf(hr, wmu[jt], pm);
            ps = fmaf(hr, wsg[jt], ps);
        }
        #pragma unroll
        for (int off = 1; off < 16; off <<= 1) {
            pm += __shfl_xor(pm, off, 64);
            ps += __shfl_xor(ps, off, 64);
        }
        if (ln == 0) {
            const int cid2 = cid0 + quad * 4 + r;
            const int n = cid2 / SEQ;
            const int t = cid2 - n * SEQ;
            const float mu = pm + bmu;
            const float sg = softplus_(ps + bsg) + 1e-6f;
            mu_out[(size_t)n * T_ALL + t] = mu;
            sg_out[(size_t)n * T_ALL + t] = sg;
            if (t == SEQ - 1) {
                const float yv = y[cid2];
                const float d  = yv - mu;
                const float is = frcp(sg);
                const float lik = 0.39894228040143267f * is * fexp(-0.5f * d * d * is * is);
                out[(size_t)n * HOR] = lik;
            }
        }
    }
}

extern "C" void kernel_launch(void* const* d_in, const int* in_sizes, int n_in,
                              void* d_out, int out_size, void* d_ws, size_t ws_size,
                              hipStream_t stream) {
    const float* X       = (const float*)d_in[0];
    const float* y       = (const float*)d_in[1];
    const float* Xf      = (const float*)d_in[2];
    const float* W_embed = (const float*)d_in[3];
    const float* b_embed = (const float*)d_in[4];
    const float* W_ih    = (const float*)d_in[5];
    const float* b_ih    = (const float*)d_in[6];
    const float* b_hh    = (const float*)d_in[7];
    const float* W_mu    = (const float*)d_in[8];
    const float* b_mu    = (const float*)d_in[9];
    const float* W_sigma = (const float*)d_in[10];
    const float* b_sigma = (const float*)d_in[11];

    float* out = (float*)d_out;
    // ws: W16f(49152 B) | bsum(1536 B) | wy1(768 B) | b1c(768 B)
    _Float16*  W16f = (_Float16*)d_ws;
    float*     bsum = (float*)((char*)d_ws + 49152);
    float*     wy1  = (float*)((char*)d_ws + 49152 + 1536);
    float*     b1c  = (float*)((char*)d_ws + 49152 + 1536 + 768);

    prep<<<96, 256, 0, stream>>>(W_ih, b_ih, b_hh, W_embed, b_embed,
                                 W16f, bsum, wy1, b1c);

    fused<<<NB_B + (N_TS * SEQ) / 64, 256, 0, stream>>>(
        X, y, Xf, W_embed, b_embed, W16f, bsum, wy1, b1c,
        W_mu, b_mu, W_sigma, b_sigma, out);
}